// Round 5
// baseline (639.017 us; speedup 1.0000x reference)
//
#include <hip/hip_runtime.h>
#include <hip/hip_bf16.h>

typedef __attribute__((ext_vector_type(8))) short short8;
typedef __attribute__((ext_vector_type(4))) float f32x4;

#define NTOP 1000
#define KC   256
#define MROWS 40000

static __device__ __forceinline__ unsigned short f2bf(float x) {
    union { float f; unsigned u; } v; v.f = x;
    unsigned r = (v.u + 0x7FFFu + ((v.u >> 16) & 1u)) >> 16;
    return (unsigned short)r;
}

// spread bits 0..7 of x to bit positions 0,4,8,...,28
static __device__ __forceinline__ unsigned spread4(unsigned x) {
    x = (x | (x << 12)) & 0x000F000Fu;
    x = (x | (x << 6))  & 0x03030303u;
    x = (x | (x << 3))  & 0x11111111u;
    return x;
}

// Kernel 1: colsum[j] += sum over an 8-row slab of nw. colsum pre-zeroed by memset.
__global__ void k_prep(const float* __restrict__ nw,
                       float* __restrict__ colsum) {
    int j  = blockIdx.x * 256 + threadIdx.x;
    int i0 = blockIdx.y * 8;
    if (j < NTOP) {
        float s = 0.f;
        int iend = min(i0 + 8, NTOP);
        for (int i = i0; i < iend; ++i) s += nw[(size_t)i * NTOP + j];
        atomicAdd(colsum + j, s);
    }
}

// Kernel 2: build B' in MFMA-fragment order:
//   B'[((nt*8 + s)*64 + lane)] (short8) = V_j[n = nt*16 + (lane&15),
//                                             k = s*32 + (lane>>4)*8 + j]
__global__ void k_vj(const float* __restrict__ V,
                     const float* __restrict__ noise,
                     const float* __restrict__ colsum,
                     unsigned short* __restrict__ Bp) {
    int t  = blockIdx.x * 256 + threadIdx.x;   // 0 .. 32767
    int nt = t >> 9;
    int s  = (t >> 6) & 7;
    int l  = t & 63;
    int lm = l & 15, lq = l >> 4;
    int n  = nt * 16 + lm;
    int k0 = s * 32 + lq * 8;
    union { short8 v; unsigned short us[8]; } pk;
    if (n < NTOP) {
        float cs = colsum[n];
        #pragma unroll
        for (int j = 0; j < 8; ++j) {
            int idx = n * KC + k0 + j;
            pk.us[j] = f2bf(V[idx] * cs + 0.1f * noise[idx]);
        }
    } else {
        #pragma unroll
        for (int j = 0; j < 8; ++j) pk.us[j] = 0;
    }
    reinterpret_cast<short8*>(Bp)[t] = pk.v;
}

// Kernel 2b (v6): ballot-based C compression. 160 MB read FULLY COALESCED
// (wave reads 1 KB contiguous per instruction), __ballot packs 256 preds,
// 8 lanes spread bytes into mask words, LDS transpose, coalesced write.
// maskT[hs][m] bit b <=> C[m][hs*32+b] == 1   (b = col mod 32).
__global__ __launch_bounds__(256) void k_cmask(const int* __restrict__ C,
                                               unsigned int* __restrict__ maskT) {
    __shared__ unsigned int lmask[32][32];   // [hs][row-in-block] 4 KB
    const int tid  = threadIdx.x;
    const int wave = tid >> 6;
    const int l    = tid & 63;
    const int rbase = blockIdx.x * 32;

    for (int rr = 0; rr < 8; ++rr) {
        const int row = wave * 8 + rr;                 // 0..31
        const int* crow = C + (size_t)(rbase + row) * NTOP;
        #pragma unroll
        for (int c = 0; c < 4; ++c) {
            const int col = c * 256 + l * 4;
            int4 v = make_int4(0, 0, 0, 0);
            if (col + 3 < NTOP) v = *reinterpret_cast<const int4*>(crow + col);
            unsigned long long b0 = __ballot(v.x == 1);
            unsigned long long b1 = __ballot(v.y == 1);
            unsigned long long b2 = __ballot(v.z == 1);
            unsigned long long b3 = __ballot(v.w == 1);
            if (l < 8) {
                unsigned w = spread4((unsigned)(b0 >> (l * 8)) & 0xffu)
                           | (spread4((unsigned)(b1 >> (l * 8)) & 0xffu) << 1)
                           | (spread4((unsigned)(b2 >> (l * 8)) & 0xffu) << 2)
                           | (spread4((unsigned)(b3 >> (l * 8)) & 0xffu) << 3);
                lmask[c * 8 + l][row] = w;
            }
        }
    }
    __syncthreads();
    // thread t: hs = t>>3, writes rows ch*4..+4 as one int4 (coalesced per hs)
    const int hs = tid >> 3, ch = tid & 7;
    *reinterpret_cast<int4*>(maskT + (size_t)hs * MROWS + rbase + ch * 4) =
        *reinterpret_cast<const int4*>(&lmask[hs][ch * 4]);
}

// ---------------- k_main v6: barrier-free, LDS-free ----------------
// M=32 rows/block, grid 1250 (single residency round at 5 blocks/CU).
// 4 INDEPENDENT waves (wr = wave>>1 row-half, wc = wave&1 col-half): no
// __syncthreads, no vmcnt(0) drains -> compiler pipelines loads across hs
// iterations; 20 waves/CU of TLP overlap VALU / MFMA / L2 / HBM pipes.
//  - Bf fragments: direct coalesced 1 KB loads from L2 (Bf = 512 KB, resident)
//  - R: direct float4 (full 64B lines)
//  - C: 1 broadcast mask line per wave per iter
__global__ __launch_bounds__(256, 5) void k_main(
    const float* __restrict__ U, const float* __restrict__ w5,
    const float* __restrict__ b1, const short8* __restrict__ Bf,
    const float* __restrict__ R, const unsigned int* __restrict__ maskT,
    float* __restrict__ out)
{
    const int tid  = threadIdx.x;
    const int wave = tid >> 6;
    const int l    = tid & 63;
    const int lm = l & 15;
    const int lq = l >> 4;
    const int wr = wave >> 1;          // row-half 0..1
    const int wc = wave & 1;           // col-half 0..1
    const int rbase = blockIdx.x << 5;
    const int m  = rbase + wr * 16 + lm;

    // ---- build this wave's 8 A-fragments (U_emb rows m) in registers ----
    const float w0 = w5[0], w1 = w5[1], w2 = w5[2], w3 = w5[3], w4 = w5[4];
    const float bb = b1[0];
    short8 afr[8];
    #pragma unroll
    for (int s = 0; s < 8; ++s) {
        const float4* up4 = reinterpret_cast<const float4*>(
            U + (size_t)(m * KC + s * 32 + lq * 8) * 5);
        float u[40];
        #pragma unroll
        for (int i = 0; i < 10; ++i) {
            float4 t4 = up4[i];
            u[i*4+0] = t4.x; u[i*4+1] = t4.y; u[i*4+2] = t4.z; u[i*4+3] = t4.w;
        }
        union { short8 v; unsigned short us[8]; } pk;
        #pragma unroll
        for (int j = 0; j < 8; ++j) {
            const float* uu = u + j * 5;
            float e = uu[0]*w0 + uu[1]*w1 + uu[2]*w2 + uu[3]*w3 + uu[4]*w4 + bb;
            pk.us[j] = f2bf(e);
        }
        afr[s] = pk.v;
    }

    float lpsum = 0.f;
    const size_t rowbase = (size_t)m * NTOP;

    for (int hs = 0; hs < 32; ++hs) {
        // mask word: 16 consecutive words per wave = 1 line, broadcast to lq
        const unsigned mw = maskT[(size_t)hs * MROWS + m];

        // R: one float4 per lane, 4 lanes (lq 0..3 share row) = one 64B line
        int nb = hs * 32 + wc * 16 + lq * 4;
        const int nbc = nb < 996 ? nb : 996;      // tail clamp; masked below
        const float4 r4 = *reinterpret_cast<const float4*>(R + rowbase + nbc);

        // fragments for n-tile nt = hs*2 + wc, K = 256
        const int nt = hs * 2 + wc;
        f32x4 acc = (f32x4){0.f, 0.f, 0.f, 0.f};
        #pragma unroll
        for (int s = 0; s < 8; ++s) {
            const short8 bfr = Bf[((nt * 8 + s) << 6) + l];
            acc = __builtin_amdgcn_mfma_f32_16x16x32_bf16(bfr, afr[s], acc, 0, 0, 0);
        }

        // Epilogue: lane holds m (fixed), n = hs*32 + wc*16 + lq*4 + r
        const float* rp = reinterpret_cast<const float*>(&r4);
        #pragma unroll
        for (int r = 0; r < 4; ++r) {
            const int bit = wc * 16 + lq * 4 + r;   // col mod 32
            float x   = acc[r];
            float muv = 1.f / (1.f + __expf(-x));
            float d   = rp[r] - muv;
            float lp  = -50.f * d * d + 1.3836465597893728f;
            if ((mw >> bit) & 1u) lpsum += lp;
        }
    }

    #pragma unroll
    for (int off = 32; off > 0; off >>= 1) lpsum += __shfl_down(lpsum, off);
    if (l == 0) atomicAdd(out, lpsum);
}

extern "C" void kernel_launch(void* const* d_in, const int* in_sizes, int n_in,
                              void* d_out, int out_size, void* d_ws, size_t ws_size,
                              hipStream_t stream) {
    const float* V     = (const float*)d_in[1];
    const float* R     = (const float*)d_in[2];
    const float* nw    = (const float*)d_in[3];
    const float* U     = (const float*)d_in[4];
    const float* w5    = (const float*)d_in[5];
    const float* b1    = (const float*)d_in[6];
    const float* noise = (const float*)d_in[7];
    const int*   C     = (const int*)d_in[8];
    float* out = (float*)d_out;

    float* colsum       = (float*)d_ws;
    unsigned short* Bp  = (unsigned short*)((char*)d_ws + 8192);
    unsigned int* maskT = (unsigned int*)((char*)d_ws + 8192 + 524288);

    hipMemsetAsync(colsum, 0, NTOP * sizeof(float), stream);
    hipMemsetAsync(out, 0, sizeof(float), stream);
    hipLaunchKernelGGL(k_prep, dim3(4, 125), dim3(256), 0, stream, nw, colsum);
    hipLaunchKernelGGL(k_vj, dim3(128), dim3(256), 0, stream,
                       V, noise, colsum, Bp);
    hipLaunchKernelGGL(k_cmask, dim3(MROWS / 32), dim3(256), 0, stream, C, maskT);
    hipLaunchKernelGGL(k_main, dim3(MROWS / 32), dim3(256), 0, stream,
                       U, w5, b1, (const short8*)Bp, R, maskT, out);
}

// Round 6
// 601.829 us; speedup vs baseline: 1.0618x; 1.0618x over previous
//
#include <hip/hip_runtime.h>
#include <hip/hip_bf16.h>

typedef __attribute__((ext_vector_type(8))) short short8;
typedef __attribute__((ext_vector_type(4))) float f32x4;

#define NTOP 1000
#define KC   256
#define MROWS 40000

static __device__ __forceinline__ unsigned short f2bf(float x) {
    union { float f; unsigned u; } v; v.f = x;
    unsigned r = (v.u + 0x7FFFu + ((v.u >> 16) & 1u)) >> 16;
    return (unsigned short)r;
}

// spread bits 0..7 of x to bit positions 0,4,8,...,28
static __device__ __forceinline__ unsigned spread4(unsigned x) {
    x = (x | (x << 12)) & 0x000F000Fu;
    x = (x | (x << 6))  & 0x03030303u;
    x = (x | (x << 3))  & 0x11111111u;
    return x;
}

// Kernel 1: colsum[j] += sum over an 8-row slab of nw. colsum pre-zeroed by memset.
__global__ void k_prep(const float* __restrict__ nw,
                       float* __restrict__ colsum) {
    int j  = blockIdx.x * 256 + threadIdx.x;
    int i0 = blockIdx.y * 8;
    if (j < NTOP) {
        float s = 0.f;
        int iend = min(i0 + 8, NTOP);
        for (int i = i0; i < iend; ++i) s += nw[(size_t)i * NTOP + j];
        atomicAdd(colsum + j, s);
    }
}

// Kernel 2: build B' in MFMA-fragment order:
//   B'[((nt*8 + s)*64 + lane)] (short8) = V_j[n = nt*16 + (lane&15),
//                                             k = s*32 + (lane>>4)*8 + j]
__global__ void k_vj(const float* __restrict__ V,
                     const float* __restrict__ noise,
                     const float* __restrict__ colsum,
                     unsigned short* __restrict__ Bp) {
    int t  = blockIdx.x * 256 + threadIdx.x;   // 0 .. 32767
    int nt = t >> 9;
    int s  = (t >> 6) & 7;
    int l  = t & 63;
    int lm = l & 15, lq = l >> 4;
    int n  = nt * 16 + lm;
    int k0 = s * 32 + lq * 8;
    union { short8 v; unsigned short us[8]; } pk;
    if (n < NTOP) {
        float cs = colsum[n];
        #pragma unroll
        for (int j = 0; j < 8; ++j) {
            int idx = n * KC + k0 + j;
            pk.us[j] = f2bf(V[idx] * cs + 0.1f * noise[idx]);
        }
    } else {
        #pragma unroll
        for (int j = 0; j < 8; ++j) pk.us[j] = 0;
    }
    reinterpret_cast<short8*>(Bp)[t] = pk.v;
}

// Kernel 2b: ballot-based C compression (coalesced 1 KB reads, 256 bits/ballot
// group, LDS transpose, coalesced writes).
// maskT[hs][m] bit b <=> C[m][hs*32+b] == 1   (b = col mod 32).
__global__ __launch_bounds__(256) void k_cmask(const int* __restrict__ C,
                                               unsigned int* __restrict__ maskT) {
    __shared__ unsigned int lmask[32][32];   // [hs][row-in-block] 4 KB
    const int tid  = threadIdx.x;
    const int wave = tid >> 6;
    const int l    = tid & 63;
    const int rbase = blockIdx.x * 32;

    for (int rr = 0; rr < 8; ++rr) {
        const int row = wave * 8 + rr;                 // 0..31
        const int* crow = C + (size_t)(rbase + row) * NTOP;
        #pragma unroll
        for (int c = 0; c < 4; ++c) {
            const int col = c * 256 + l * 4;
            int4 v = make_int4(0, 0, 0, 0);
            if (col + 3 < NTOP) v = *reinterpret_cast<const int4*>(crow + col);
            unsigned long long b0 = __ballot(v.x == 1);
            unsigned long long b1 = __ballot(v.y == 1);
            unsigned long long b2 = __ballot(v.z == 1);
            unsigned long long b3 = __ballot(v.w == 1);
            if (l < 8) {
                unsigned w = spread4((unsigned)(b0 >> (l * 8)) & 0xffu)
                           | (spread4((unsigned)(b1 >> (l * 8)) & 0xffu) << 1)
                           | (spread4((unsigned)(b2 >> (l * 8)) & 0xffu) << 2)
                           | (spread4((unsigned)(b3 >> (l * 8)) & 0xffu) << 3);
                lmask[c * 8 + l][row] = w;
            }
        }
    }
    __syncthreads();
    const int hs = tid >> 3, ch = tid & 7;
    *reinterpret_cast<int4*>(maskT + (size_t)hs * MROWS + rbase + ch * 4) =
        *reinterpret_cast<const int4*>(&lmask[hs][ch * 4]);
}

// ---------------- k_main v7 ----------------
// M=32 rows/block, grid 1250. 4 waves = (wr m-half, wc n-half).
// LDS = Bf double-buffer ONLY (2 x 16 KB = 32 KB) -> 5 blocks/CU, whole grid
// co-resident in ONE round (~61% occ). Streams:
//  - Bf: async global_load_lds, double-buffered (no VGPR dependency chain)
//  - R : direct float4, prefetched at iteration top (latency under 8 MFMAs)
//  - C : 1 broadcast mask line per wave per iter
__global__ __launch_bounds__(256, 5) void k_main(
    const float* __restrict__ U, const float* __restrict__ w5,
    const float* __restrict__ b1, const short8* __restrict__ Bf,
    const float* __restrict__ R, const unsigned int* __restrict__ maskT,
    float* __restrict__ out)
{
    __shared__ short8 BfL[2][1024];   // 2 x 16 KB (32-col tile = 2 nt x 8 s x 1KB)

    const int tid  = threadIdx.x;
    const int wave = tid >> 6;
    const int l    = tid & 63;
    const int lm = l & 15;
    const int lq = l >> 4;
    const int wr = wave >> 1;          // m-half
    const int wc = wave & 1;           // n-half
    const int m  = (blockIdx.x << 5) + (wr << 4) + lm;

    auto stageBf = [&](int buf, int hs) {
        const char* src = (const char*)Bf + ((size_t)hs << 14) + (size_t)tid * 16;
        char*       dst = (char*)&BfL[buf][0] + (size_t)tid * 16;
        #pragma unroll
        for (int i = 0; i < 4; ++i) {
            __builtin_amdgcn_global_load_lds(
                (const __attribute__((address_space(1))) unsigned int*)(src + i * 4096),
                (__attribute__((address_space(3))) unsigned int*)(dst + i * 4096),
                16, 0, 0);
        }
    };

    // prologue: stage hs=0; A-fragment build hides the latency
    stageBf(0, 0);

    const float w0 = w5[0], w1 = w5[1], w2 = w5[2], w3 = w5[3], w4 = w5[4];
    const float bb = b1[0];
    short8 afr[8];
    #pragma unroll
    for (int s = 0; s < 8; ++s) {
        const float4* up4 = reinterpret_cast<const float4*>(
            U + (size_t)(m * KC + s * 32 + lq * 8) * 5);
        float u[40];
        #pragma unroll
        for (int i = 0; i < 10; ++i) {
            float4 t4 = up4[i];
            u[i*4+0] = t4.x; u[i*4+1] = t4.y; u[i*4+2] = t4.z; u[i*4+3] = t4.w;
        }
        union { short8 v; unsigned short us[8]; } pk;
        #pragma unroll
        for (int j = 0; j < 8; ++j) {
            const float* uu = u + j * 5;
            float e = uu[0]*w0 + uu[1]*w1 + uu[2]*w2 + uu[3]*w3 + uu[4]*w4 + bb;
            pk.us[j] = f2bf(e);
        }
        afr[s] = pk.v;
    }

    __syncthreads();   // buf0 staged

    float lpsum = 0.f;
    const size_t rowbase = (size_t)m * NTOP;

    for (int hs = 0; hs < 32; ++hs) {
        const int cur = hs & 1;

        // broadcast mask word + direct R prefetch (latency hidden under MFMAs)
        const unsigned mw = maskT[(size_t)hs * MROWS + m];
        int nb = hs * 32 + wc * 16 + lq * 4;
        const int nbc = nb < 996 ? nb : 996;      // tail clamp; masked below
        const float4 r4 = *reinterpret_cast<const float4*>(R + rowbase + nbc);

        if (hs < 31) stageBf(cur ^ 1, hs + 1);

        f32x4 acc = (f32x4){0.f, 0.f, 0.f, 0.f};
        #pragma unroll
        for (int s = 0; s < 8; ++s) {
            const short8 bfr = BfL[cur][((wc * 8 + s) << 6) + l];
            acc = __builtin_amdgcn_mfma_f32_16x16x32_bf16(bfr, afr[s], acc, 0, 0, 0);
        }

        // Epilogue: lane holds m (fixed), n = hs*32 + wc*16 + lq*4 + r
        const float* rp = reinterpret_cast<const float*>(&r4);
        #pragma unroll
        for (int r = 0; r < 4; ++r) {
            const int bit = wc * 16 + lq * 4 + r;   // col mod 32
            float x   = acc[r];
            float muv = 1.f / (1.f + __expf(-x));
            float d   = rp[r] - muv;
            float lp  = -50.f * d * d + 1.3836465597893728f;
            if ((mw >> bit) & 1u) lpsum += lp;
        }

        __syncthreads();   // readers done with cur; stage(hs+1) drained
    }

    #pragma unroll
    for (int off = 32; off > 0; off >>= 1) lpsum += __shfl_down(lpsum, off);
    if (l == 0) atomicAdd(out, lpsum);
}

extern "C" void kernel_launch(void* const* d_in, const int* in_sizes, int n_in,
                              void* d_out, int out_size, void* d_ws, size_t ws_size,
                              hipStream_t stream) {
    const float* V     = (const float*)d_in[1];
    const float* R     = (const float*)d_in[2];
    const float* nw    = (const float*)d_in[3];
    const float* U     = (const float*)d_in[4];
    const float* w5    = (const float*)d_in[5];
    const float* b1    = (const float*)d_in[6];
    const float* noise = (const float*)d_in[7];
    const int*   C     = (const int*)d_in[8];
    float* out = (float*)d_out;

    float* colsum       = (float*)d_ws;
    unsigned short* Bp  = (unsigned short*)((char*)d_ws + 8192);
    unsigned int* maskT = (unsigned int*)((char*)d_ws + 8192 + 524288);

    hipMemsetAsync(colsum, 0, NTOP * sizeof(float), stream);
    hipMemsetAsync(out, 0, sizeof(float), stream);
    hipLaunchKernelGGL(k_prep, dim3(4, 125), dim3(256), 0, stream, nw, colsum);
    hipLaunchKernelGGL(k_vj, dim3(128), dim3(256), 0, stream,
                       V, noise, colsum, Bp);
    hipLaunchKernelGGL(k_cmask, dim3(MROWS / 32), dim3(256), 0, stream, C, maskT);
    hipLaunchKernelGGL(k_main, dim3(MROWS / 32), dim3(256), 0, stream,
                       U, w5, b1, (const short8*)Bp, R, maskT, out);
}